// Round 9
// baseline (170.507 us; speedup 1.0000x reference)
//
#include <hip/hip_runtime.h>
#include <hip/hip_bf16.h>
#include <cstdint>

typedef unsigned short u16;
typedef __attribute__((ext_vector_type(8))) short bf16x8;
typedef __attribute__((ext_vector_type(4))) float f32x4;

#define AS1 __attribute__((address_space(1)))
#define AS3 __attribute__((address_space(3)))

// 0.125 (1/sqrt(64)) * log2(e): folds softmax scale AND exp->exp2 conversion
#define QSCALE_CONST 0.18033688011112042f
// fixed softmax "max" (log2 domain), folded into the QK^T accumulator init.
#define SMAX_CONST 8.0f

__device__ __forceinline__ u16 f2bf(float f) {
  union { float f; unsigned u; } v; v.f = f;
  unsigned u = v.u;
  return (u16)((u + 0x7fffu + ((u >> 16) & 1u)) >> 16);
}

// async global->LDS, 16B per lane; pass WAVE-UNIFORM LDS base (HW adds lane*16)
__device__ __forceinline__ void gload_lds16(const void* g, const void* l) {
  __builtin_amdgcn_global_load_lds(
      (const AS1 unsigned int*)(uintptr_t)g,
      (AS3 unsigned int*)(unsigned int)(uintptr_t)l,
      16, 0, 0);
}

// ---------------- cast fp32 -> bf16 (vectorized) ----------------
__global__ __launch_bounds__(256) void cast_bf16_kernel(
    const float* __restrict__ in, u16* __restrict__ out, int n) {
  int i = (blockIdx.x * 256 + threadIdx.x) * 4;
  if (i >= n) return;
  float4 f = *(const float4*)(in + i);
  ushort4 o;
  o.x = f2bf(f.x); o.y = f2bf(f.y); o.z = f2bf(f.z); o.w = f2bf(f.w);
  *(ushort4*)(out + i) = o;
}

// ---------------- transpose + cast: out[c][r] = bf16(in[r][c]) ----------------
__global__ __launch_bounds__(256) void transpose_cast_kernel(
    const float* __restrict__ in, u16* __restrict__ outT, int R, int C) {
  __shared__ float tile[32][33];
  const int c0 = blockIdx.x << 5, r0 = blockIdx.y << 5;
  const int x = threadIdx.x & 31, y = threadIdx.x >> 5;
#pragma unroll
  for (int yy = y; yy < 32; yy += 8)
    tile[yy][x] = in[(size_t)(r0 + yy) * C + c0 + x];
  __syncthreads();
#pragma unroll
  for (int yy = y; yy < 32; yy += 8)
    outT[(size_t)(c0 + yy) * R + r0 + x] = f2bf(tile[x][yy]);
}

// ======== 256x256 8-wave phase-interleaved GEMM (T2+T3+T4+T5 regime) ========
// C[M,N] = A[M,K] * Bt[N,K]^T + bias. BK=32, 3-buffer LDS ring (96 KB),
// prefetch distance 2, counted vmcnt(4) (never 0 until tail). 8 waves 2Mx4N,
// wave tile 128x64 (8x4 frags): 12 ds_read_b128 per 32 MFMA. Two phases per
// K-tile: {ds_read + stage-issue; barrier; lgkmcnt(0); setprio MFMA; barrier}.
__global__ __launch_bounds__(512, 2) void gemm256_kernel(
    const u16* __restrict__ A, const u16* __restrict__ Bt,
    const float* __restrict__ bias, u16* __restrict__ Cmat,
    int M, int N, int K, int qcols) {
  __shared__ __attribute__((aligned(16))) u16 As[3][256 * 32];
  __shared__ __attribute__((aligned(16))) u16 Bs[3][256 * 32];

  const int nbn = N >> 8;
  const int nwg = (M >> 8) * nbn;
  int bid = blockIdx.x;
  if ((nwg & 7) == 0) {                 // XCD swizzle (384 % 8 == 0)
    int cpx = nwg >> 3;
    bid = (bid & 7) * cpx + (bid >> 3);
  }
  const int bm = bid / nbn, bn = bid % nbn;

  const int tid = threadIdx.x;
  const int lane = tid & 63, wave = tid >> 6;
  const int g = lane >> 4, l15 = lane & 15;
  const int wm = wave >> 2, wn = wave & 3;   // wave tile: rows wm*128, cols wn*64

  const u16* Abase = A + (size_t)(bm << 8) * K;
  const u16* Bbase = Bt + (size_t)(bn << 8) * K;

  // staging ids: chunks c0=tid (rows 0..127), c1=512+tid (rows 128..255)
  const int c0_ = tid, c1_ = 512 + tid;
  const int r0_ = c0_ >> 2, r1_ = c1_ >> 2;
  const size_t soff0 = (size_t)r0_ * K + ((c0_ & 3) ^ (r0_ & 3)) * 8;
  const size_t soff1 = (size_t)r1_ * K + ((c1_ & 3) ^ (r1_ & 3)) * 8;
  const int doff0 = c0_ * 8, doff1 = c1_ * 8;

  auto stageA = [&](int buf, int k0) {
    gload_lds16(Abase + k0 + soff0, As[buf] + doff0);
    gload_lds16(Abase + k0 + soff1, As[buf] + doff1);
  };
  auto stageB = [&](int buf, int k0) {
    gload_lds16(Bbase + k0 + soff0, Bs[buf] + doff0);
    gload_lds16(Bbase + k0 + soff1, Bs[buf] + doff1);
  };

  f32x4 zero = {0.f, 0.f, 0.f, 0.f};
  f32x4 acc[8][4];
#pragma unroll
  for (int i = 0; i < 8; ++i)
#pragma unroll
    for (int j = 0; j < 4; ++j) acc[i][j] = zero;

  const int NT = K >> 5;   // 32
  stageA(0, 0); stageB(0, 0);
  stageA(1, 32); stageB(1, 32);
  asm volatile("s_waitcnt vmcnt(4)" ::: "memory");   // tile 0 landed (4 newest fly)
  __builtin_amdgcn_s_barrier();
  __builtin_amdgcn_sched_barrier(0);

#pragma unroll 1
  for (int kt = 0; kt < NT; ++kt) {
    const int cur = kt % 3, nxt = (kt + 2) % 3;
    const char* Ab = (const char*)As[cur];
    const char* Bb = (const char*)Bs[cur];

    // ---------------- phase 0: A rows 0..63 of wave tile, all B ----------------
    bf16x8 af[4], bfr[4];
#pragma unroll
    for (int i = 0; i < 4; ++i) {
      int ra = wm * 128 + i * 16 + l15;
      af[i] = *(const bf16x8*)(Ab + ra * 64 + ((g ^ (ra & 3)) << 4));
    }
#pragma unroll
    for (int j = 0; j < 4; ++j) {
      int rb = wn * 64 + j * 16 + l15;
      bfr[j] = *(const bf16x8*)(Bb + rb * 64 + ((g ^ (rb & 3)) << 4));
    }
    if (kt + 2 < NT) stageA(nxt, (kt + 2) << 5);
    __builtin_amdgcn_s_barrier();
    asm volatile("s_waitcnt lgkmcnt(0)" ::: "memory");
    __builtin_amdgcn_sched_barrier(0);
    __builtin_amdgcn_s_setprio(1);
#pragma unroll
    for (int i = 0; i < 4; ++i)
#pragma unroll
      for (int j = 0; j < 4; ++j)
        acc[i][j] = __builtin_amdgcn_mfma_f32_16x16x32_bf16(af[i], bfr[j], acc[i][j], 0, 0, 0);
    __builtin_amdgcn_s_setprio(0);
    __builtin_amdgcn_s_barrier();
    __builtin_amdgcn_sched_barrier(0);

    // ---------------- phase 1: A rows 64..127 of wave tile ----------------
    bf16x8 ag[4];
#pragma unroll
    for (int i = 0; i < 4; ++i) {
      int ra = wm * 128 + (i + 4) * 16 + l15;
      ag[i] = *(const bf16x8*)(Ab + ra * 64 + ((g ^ (ra & 3)) << 4));
    }
    if (kt + 2 < NT) stageB(nxt, (kt + 2) << 5);
    __builtin_amdgcn_s_barrier();
    asm volatile("s_waitcnt lgkmcnt(0)" ::: "memory");
    __builtin_amdgcn_sched_barrier(0);
    __builtin_amdgcn_s_setprio(1);
#pragma unroll
    for (int i = 0; i < 4; ++i)
#pragma unroll
      for (int j = 0; j < 4; ++j)
        acc[i + 4][j] = __builtin_amdgcn_mfma_f32_16x16x32_bf16(ag[i], bfr[j], acc[i + 4][j], 0, 0, 0);
    __builtin_amdgcn_s_setprio(0);
    // tile boundary: publish tile kt+1 (counted; 0 only at the tail)
    if (kt < NT - 2)       asm volatile("s_waitcnt vmcnt(4)" ::: "memory");
    else if (kt == NT - 2) asm volatile("s_waitcnt vmcnt(0)" ::: "memory");
    __builtin_amdgcn_s_barrier();
    __builtin_amdgcn_sched_barrier(0);
  }

#pragma unroll
  for (int i = 0; i < 8; ++i) {
    int row0 = (bm << 8) + wm * 128 + i * 16 + g * 4;
#pragma unroll
    for (int j = 0; j < 4; ++j) {
      int col = (bn << 8) + wn * 64 + j * 16 + l15;
      float bv = bias[col];
      const bool qc = col < qcols;
#pragma unroll
      for (int r = 0; r < 4; ++r) {
        float v = acc[i][j][r] + bv;
        if (qc) v *= QSCALE_CONST;
        Cmat[(size_t)(row0 + r) * N + col] = f2bf(v);
      }
    }
  }
}

// ---------------- 128x128 bf16 GEMM (ring), used for the small GEMM2 ----------------
template <typename OutT>
__global__ __launch_bounds__(256, 3) void gemm_bf16_kernel(
    const u16* __restrict__ A, const u16* __restrict__ Bt,
    const float* __restrict__ bias, OutT* __restrict__ Cmat,
    int M, int N, int K, int qcols) {
  __shared__ __attribute__((aligned(16))) u16 As[3][128 * 32];
  __shared__ __attribute__((aligned(16))) u16 Bs[3][128 * 32];

  const int nbn = N >> 7;
  const int nwg = (M >> 7) * nbn;
  int bid = blockIdx.x;
  if ((nwg & 7) == 0) {
    int cpx = nwg >> 3;
    bid = (bid & 7) * cpx + (bid >> 3);
  }
  const int bm = bid / nbn, bn = bid % nbn;

  const int tid = threadIdx.x;
  const int lane = tid & 63, wave = tid >> 6;
  const int g = lane >> 4, l15 = lane & 15;
  const int wrow = (wave >> 1) << 6, wcol = (wave & 1) << 6;

  const u16* Abase = A + (size_t)(bm << 7) * K;
  const u16* Bbase = Bt + (size_t)(bn << 7) * K;

  const int c0_ = wave * 64 + lane, c1_ = 256 + c0_;
  const int row0_ = c0_ >> 2, row1_ = c1_ >> 2;
  const size_t soff0 = (size_t)row0_ * K + ((c0_ & 3) ^ (row0_ & 3)) * 8;
  const size_t soff1 = (size_t)row1_ * K + ((c1_ & 3) ^ (row1_ & 3)) * 8;
  const int doff0 = c0_ * 8, doff1 = c1_ * 8;

  auto stage = [&](int buf, int k0) {
    gload_lds16(Abase + k0 + soff0, As[buf] + doff0);
    gload_lds16(Bbase + k0 + soff0, Bs[buf] + doff0);
    gload_lds16(Abase + k0 + soff1, As[buf] + doff1);
    gload_lds16(Bbase + k0 + soff1, Bs[buf] + doff1);
  };

  f32x4 zero = {0.f, 0.f, 0.f, 0.f};
  f32x4 acc[4][4];
#pragma unroll
  for (int i = 0; i < 4; ++i)
#pragma unroll
    for (int j = 0; j < 4; ++j) acc[i][j] = zero;

  const int NT = K >> 5;
  stage(0, 0);
  stage(1, 32);
#pragma unroll 1
  for (int kt = 0; kt < NT; ++kt) {
    const int cur = kt % 3;
    asm volatile("s_waitcnt lgkmcnt(0)" ::: "memory");
    __builtin_amdgcn_sched_barrier(0);
    if (kt < NT - 1) asm volatile("s_waitcnt vmcnt(4)" ::: "memory");
    else             asm volatile("s_waitcnt vmcnt(0)" ::: "memory");
    __builtin_amdgcn_s_barrier();
    if (kt + 2 < NT) stage((kt + 2) % 3, (kt + 2) << 5);

    const char* Ab = (const char*)As[cur];
    const char* Bb = (const char*)Bs[cur];
    bf16x8 af[4], bfr[4];
#pragma unroll
    for (int i = 0; i < 4; ++i) {
      int ra = wrow + i * 16 + l15;
      af[i] = *(const bf16x8*)(Ab + ra * 64 + ((g * 16) ^ ((ra & 3) << 4)));
      int rb = wcol + i * 16 + l15;
      bfr[i] = *(const bf16x8*)(Bb + rb * 64 + ((g * 16) ^ ((rb & 3) << 4)));
    }
#pragma unroll
    for (int i = 0; i < 4; ++i)
#pragma unroll
      for (int j = 0; j < 4; ++j)
        acc[i][j] = __builtin_amdgcn_mfma_f32_16x16x32_bf16(af[i], bfr[j], acc[i][j], 0, 0, 0);
  }

#pragma unroll
  for (int i = 0; i < 4; ++i) {
    int row0 = (bm << 7) + wrow + i * 16 + g * 4;
#pragma unroll
    for (int j = 0; j < 4; ++j) {
      int col = (bn << 7) + wcol + j * 16 + l15;
      float bv = bias[col];
      const bool qc = col < qcols;
#pragma unroll
      for (int r = 0; r < 4; ++r) {
        float v = acc[i][j][r] + bv;
        if (qc) v *= QSCALE_CONST;
        size_t idx = (size_t)(row0 + r) * N + col;
        if constexpr (sizeof(OutT) == 2)
          ((u16*)Cmat)[idx] = f2bf(v);
        else
          ((float*)Cmat)[idx] = v;
      }
    }
  }
}

// ---------------- flash attention v6 (causal), B=4 H=16 T=2048 Dh=64 ----------------
// grid (B*H=64, 8), 256 threads (4 waves). Wave owns 32 q-rows (two 16-row
// groups A/B) -> each K/V LDS fragment read feeds TWO MFMAs. blockIdx.x = bh
// -> same-head blocks on same XCD. Supertile pair {j, 15-j}: uniform 36 steps.
// Swapped QK^T, fixed-max softmax folded into acc init, cvt_pk P pack.
__global__ __launch_bounds__(256, 2) void attn_kernel(
    const u16* __restrict__ qkv, u16* __restrict__ aout) {
  __shared__ __attribute__((aligned(16))) char KsB[2][8192];  // K tile [64kv][64d]
  __shared__ __attribute__((aligned(16))) char VtB[2][8192];  // V^T [64d][64kv]
  __shared__ __attribute__((aligned(16))) char PbB[4][4096];  // per-wave P [32q][64kv]

  const int bh = blockIdx.x;
  const int b = bh >> 4, h = bh & 15;
  const int tid = threadIdx.x, lane = tid & 63, wave = tid >> 6;
  const int g = lane >> 4, l15 = lane & 15;

  const u16* qbase = qkv + (size_t)b * 2048 * 3072 + h * 64;
  const u16* kbase = qbase + 1024;
  const u16* vbase = qbase + 2048;

  const int krow0 = tid >> 3;
  const int ksc = (tid & 7) ^ (krow0 & 7);
  const size_t ksrc0 = (size_t)krow0 * 3072 + ksc * 8;
  const size_t ksrc1 = ksrc0 + (size_t)32 * 3072;
  const int vp_ = tid >> 3, vdh = tid & 7;
  const size_t vsrc = (size_t)(2 * vp_) * 3072 + vdh * 8;
  const int vkc = vp_ >> 2, vofs = (vp_ & 3) << 2;

  char* pb = PbB[wave];
  const f32x4 sinit = {-SMAX_CONST, -SMAX_CONST, -SMAX_CONST, -SMAX_CONST};
  f32x4 zero = {0.f, 0.f, 0.f, 0.f};

#pragma unroll 1
  for (int jj = 0; jj < 2; ++jj) {
    const int j = jj ? (15 - blockIdx.y) : blockIdx.y;
    const int q0 = j << 7;
    const int qrow = q0 + wave * 32;
    const int nt = 2 * j + 2;

    bf16x8 qfA[2], qfB[2];
#pragma unroll
    for (int kf = 0; kf < 2; ++kf) {
      qfA[kf] = *(const bf16x8*)(qbase + (size_t)(qrow + l15) * 3072 + kf * 32 + g * 8);
      qfB[kf] = *(const bf16x8*)(qbase + (size_t)(qrow + 16 + l15) * 3072 + kf * 32 + g * 8);
    }

    float lsumA = 0.f, lsumB = 0.f;
    f32x4 oA[4], oB[4];
#pragma unroll
    for (int d = 0; d < 4; ++d) { oA[d] = zero; oB[d] = zero; }

    gload_lds16(kbase + ksrc0, KsB[0] + wave * 1024);
    gload_lds16(kbase + ksrc1, KsB[0] + 4096 + wave * 1024);
    {
      bf16x8 v0 = *(const bf16x8*)(vbase + vsrc);
      bf16x8 v1 = *(const bf16x8*)(vbase + vsrc + 3072);
      char* vb = VtB[0];
#pragma unroll
      for (int q = 0; q < 8; ++q) {
        int d = vdh * 8 + q;
        int sig = q ^ vdh;
        unsigned pack = (unsigned)(u16)v0[q] | ((unsigned)(u16)v1[q] << 16);
        *(unsigned*)(vb + d * 128 + ((vkc ^ sig) << 4) + vofs) = pack;
      }
    }

    bf16x8 nv0, nv1;
#pragma unroll 1
    for (int t = 0; t < nt; ++t) {
      const int cur = t & 1;
      const int kv0 = t << 6;
      const bool pre = (t + 1 < nt);
      __syncthreads();

      if (pre) {
        const size_t nxt = (size_t)(t + 1) * 196608;
        gload_lds16(kbase + nxt + ksrc0, KsB[cur ^ 1] + wave * 1024);
        gload_lds16(kbase + nxt + ksrc1, KsB[cur ^ 1] + 4096 + wave * 1024);
        nv0 = *(const bf16x8*)(vbase + nxt + vsrc);
        nv1 = *(const bf16x8*)(vbase + nxt + vsrc + 3072);
      }

      if (qrow + 31 >= kv0) {
        const char* ks = KsB[cur];
        f32x4 sA[4], sB[4];
#pragma unroll
        for (int n = 0; n < 4; ++n) { sA[n] = sinit; sB[n] = sinit; }
#pragma unroll
        for (int kf = 0; kf < 2; ++kf)
#pragma unroll
          for (int n = 0; n < 4; ++n) {
            int row = n * 16 + l15;
            bf16x8 kfr = *(const bf16x8*)(ks + row * 128 + (((kf * 4 + g) ^ (row & 7)) << 4));
            sA[n] = __builtin_amdgcn_mfma_f32_16x16x32_bf16(kfr, qfA[kf], sA[n], 0, 0, 0);
            sB[n] = __builtin_amdgcn_mfma_f32_16x16x32_bf16(kfr, qfB[kf], sB[n], 0, 0, 0);
          }

        const int kvb = kv0 + g * 4;
        if (kv0 + 63 > qrow) {
          const int qgA = qrow + l15;
#pragma unroll
          for (int n = 0; n < 4; ++n)
#pragma unroll
            for (int r = 0; r < 4; ++r)
              if (kvb + n * 16 + r > qgA) sA[n][r] = -1e30f;
        }
        if (kv0 + 63 > qrow + 16) {
          const int qgB = qrow + 16 + l15;
#pragma unroll
          for (int n = 0; n < 4; ++n)
#pragma unroll
            for (int r = 0; r < 4; ++r)
              if (kvb + n * 16 + r > qgB) sB[n][r] = -1e30f;
        }

        float rsA = 0.f, rsB = 0.f;
#pragma unroll
        for (int n = 0; n < 4; ++n)
#pragma unroll
          for (int r = 0; r < 4; ++r) {
            float pA = __builtin_amdgcn_exp2f(sA[n][r]);
            float pB = __builtin_amdgcn_exp2f(sB[n][r]);
            sA[n][r] = pA; rsA += pA;
            sB[n][r] = pB; rsB += pB;
          }
        lsumA += rsA; lsumB += rsB;

#pragma unroll
        for (int n = 0; n < 4; ++n) {
          uint2 wA, wB;
          asm("v_cvt_pk_bf16_f32 %0, %1, %2" : "=v"(wA.x) : "v"(sA[n][0]), "v"(sA[n][1]));
          asm("v_cvt_pk_bf16_f32 %0, %1, %2" : "=v"(wA.y) : "v"(sA[n][2]), "v"(sA[n][3]));
          asm("v_cvt_pk_bf16_f32 %0, %1, %2" : "=v"(wB.x) : "v"(sB[n][0]), "v"(sB[n][1]));
          asm("v_cvt_pk_bf16_f32 %0, %1, %2" : "=v"(wB.y) : "v"(sB[n][2]), "v"(sB[n][3]));
          int c = n * 2 + (g >> 1);
          int boff = (((c ^ (l15 & 7)) << 4) | ((g & 1) << 3)) + l15 * 128;
          *(uint2*)(pb + boff) = wA;
          *(uint2*)(pb + 2048 + boff) = wB;
        }

        const char* vt = VtB[cur];
        bf16x8 pfA[2], pfB[2];
#pragma unroll
        for (int kf = 0; kf < 2; ++kf) {
          int poff = l15 * 128 + (((kf * 4 + g) ^ (l15 & 7)) << 4);
          pfA[kf] = *(const bf16x8*)(pb + poff);
          pfB[kf] = *(const bf16x8*)(pb + 2048 + poff);
        }
#pragma unroll
        for (int kf = 0; kf < 2; ++kf)
#pragma unroll
          for (int d = 0; d < 4; ++d) {
            int dr = d * 16 + l15;
            int sig = (dr & 7) ^ ((dr >> 3) & 7);
            bf16x8 vf = *(const bf16x8*)(vt + dr * 128 + (((kf * 4 + g) ^ sig) << 4));
            oA[d] = __builtin_amdgcn_mfma_f32_16x16x32_bf16(pfA[kf], vf, oA[d], 0, 0, 0);
            oB[d] = __builtin_amdgcn_mfma_f32_16x16x32_bf16(pfB[kf], vf, oB[d], 0, 0, 0);
          }
      }

      if (pre) {
        char* vb = VtB[cur ^ 1];
#pragma unroll
        for (int q = 0; q < 8; ++q) {
          int d = vdh * 8 + q;
          int sig = q ^ vdh;
          unsigned pack = (unsigned)(u16)nv0[q] | ((unsigned)(u16)nv1[q] << 16);
          *(unsigned*)(vb + d * 128 + ((vkc ^ sig) << 4) + vofs) = pack;
        }
      }
    }

    lsumA += __shfl_xor(lsumA, 16); lsumA += __shfl_xor(lsumA, 32);
    lsumB += __shfl_xor(lsumB, 16); lsumB += __shfl_xor(lsumB, 32);
    float invA[4], invB[4];
#pragma unroll
    for (int r = 0; r < 4; ++r) {
      invA[r] = __builtin_amdgcn_rcpf(__shfl(lsumA, g * 4 + r));
      invB[r] = __builtin_amdgcn_rcpf(__shfl(lsumB, g * 4 + r));
    }
    const size_t obase = (size_t)(b * 2048 + qrow) * 1024 + h * 64;
#pragma unroll
    for (int d = 0; d < 4; ++d)
#pragma unroll
      for (int r = 0; r < 4; ++r) {
        aout[obase + (size_t)(g * 4 + r) * 1024 + d * 16 + l15] = f2bf(oA[d][r] * invA[r]);
        aout[obase + (size_t)(16 + g * 4 + r) * 1024 + d * 16 + l15] = f2bf(oB[d][r] * invB[r]);
      }
  }
}

// ---------------- host launch ----------------
extern "C" void kernel_launch(void* const* d_in, const int* in_sizes, int n_in,
                              void* d_out, int out_size, void* d_ws, size_t ws_size,
                              hipStream_t stream) {
  const float* x      = (const float*)d_in[0];
  const float* W_attn = (const float*)d_in[1];
  const float* b_attn = (const float*)d_in[2];
  const float* W_proj = (const float*)d_in[3];
  const float* b_proj = (const float*)d_in[4];
  float* out = (float*)d_out;

  char* ws = (char*)d_ws;
  u16* xb   = (u16*)(ws);                                // 16 MB: x bf16 [8192,1024]
  u16* Wat  = (u16*)(ws + (size_t)16 * 1024 * 1024);     //  6 MB: W_attn^T bf16 [3072,1024]
  u16* Wpt  = (u16*)(ws + (size_t)22 * 1024 * 1024);     //  2 MB: W_proj^T bf16 [1024,1024]
  u16* qkv  = (u16*)(ws + (size_t)24 * 1024 * 1024);     // 48 MB: qkv bf16 [8192,3072] (q pre-scaled)
  u16* aout = (u16*)(ws + (size_t)72 * 1024 * 1024);     // 16 MB: attn out bf16 [8192,1024]

  cast_bf16_kernel<<<8192, 256, 0, stream>>>(x, xb, 8388608);
  transpose_cast_kernel<<<dim3(96, 32), 256, 0, stream>>>(W_attn, Wat, 1024, 3072);
  transpose_cast_kernel<<<dim3(32, 32), 256, 0, stream>>>(W_proj, Wpt, 1024, 1024);
  gemm256_kernel<<<384, 512, 0, stream>>>(xb, Wat, b_attn, qkv, 8192, 3072, 1024, 1024);
  attn_kernel<<<dim3(64, 8), 256, 0, stream>>>(qkv, aout);
  gemm_bf16_kernel<float><<<512, 256, 0, stream>>>(aout, Wpt, b_proj, out, 8192, 1024, 1024, 0);
}

// Round 10
// 166.240 us; speedup vs baseline: 1.0257x; 1.0257x over previous
//
#include <hip/hip_runtime.h>
#include <hip/hip_bf16.h>
#include <cstdint>

typedef unsigned short u16;
typedef __attribute__((ext_vector_type(8))) short bf16x8;
typedef __attribute__((ext_vector_type(4))) float f32x4;

#define AS1 __attribute__((address_space(1)))
#define AS3 __attribute__((address_space(3)))

// 0.125 (1/sqrt(64)) * log2(e): folds softmax scale AND exp->exp2 conversion
#define QSCALE_CONST 0.18033688011112042f
// fixed softmax "max" (log2 domain), folded into the QK^T accumulator init.
#define SMAX_CONST 8.0f

__device__ __forceinline__ u16 f2bf(float f) {
  union { float f; unsigned u; } v; v.f = f;
  unsigned u = v.u;
  return (u16)((u + 0x7fffu + ((u >> 16) & 1u)) >> 16);
}

// async global->LDS, 16B per lane; pass WAVE-UNIFORM LDS base (HW adds lane*16)
__device__ __forceinline__ void gload_lds16(const void* g, const void* l) {
  __builtin_amdgcn_global_load_lds(
      (const AS1 unsigned int*)(uintptr_t)g,
      (AS3 unsigned int*)(unsigned int)(uintptr_t)l,
      16, 0, 0);
}

// ---------------- cast fp32 -> bf16 (vectorized) ----------------
__global__ __launch_bounds__(256) void cast_bf16_kernel(
    const float* __restrict__ in, u16* __restrict__ out, int n) {
  int i = (blockIdx.x * 256 + threadIdx.x) * 4;
  if (i >= n) return;
  float4 f = *(const float4*)(in + i);
  ushort4 o;
  o.x = f2bf(f.x); o.y = f2bf(f.y); o.z = f2bf(f.z); o.w = f2bf(f.w);
  *(ushort4*)(out + i) = o;
}

// ---------------- transpose + cast: out[c][r] = bf16(in[r][c]) ----------------
__global__ __launch_bounds__(256) void transpose_cast_kernel(
    const float* __restrict__ in, u16* __restrict__ outT, int R, int C) {
  __shared__ float tile[32][33];
  const int c0 = blockIdx.x << 5, r0 = blockIdx.y << 5;
  const int x = threadIdx.x & 31, y = threadIdx.x >> 5;
#pragma unroll
  for (int yy = y; yy < 32; yy += 8)
    tile[yy][x] = in[(size_t)(r0 + yy) * C + c0 + x];
  __syncthreads();
#pragma unroll
  for (int yy = y; yy < 32; yy += 8)
    outT[(size_t)(c0 + yy) * R + r0 + x] = f2bf(tile[x][yy]);
}

// ======== 256x256 BK=64 four-phase GEMM (m201-style; T2+T3+T4+T5) ========
// C[M,N] = A[M,K]*Bt[N,K]^T + bias. 8 waves 2Mx4N, wave tile 128x64.
// LDS 128KB: 2 bufs x 4 regions {A_kh0,A_kh1,B_kh0,B_kh1} of 16KB.
// Stage group S = {A_khX, B_khX} of one tile = 4 gloads/thread.
// Issue: S(kh0,t+1) at P1 of t; S(kh1,t+1) at P3 of t.
// Publish: end-P2 vmcnt(4) -> kh1(t) landed; end-P4 vmcnt(4) -> kh0(t+1).
// In-flight <= 2 groups (8 loads) so vmcnt(4) always frees the oldest group.
__global__ __launch_bounds__(512, 2) void gemm256_kernel(
    const u16* __restrict__ A, const u16* __restrict__ Bt,
    const float* __restrict__ bias, u16* __restrict__ Cmat,
    int M, int N, int K, int qcols) {
  __shared__ __attribute__((aligned(16))) u16 L[2][4][8192]; // [buf][reg][16KB]

  const int nbn = N >> 8;
  const int nwg = (M >> 8) * nbn;
  int bid = blockIdx.x;
  if ((nwg & 7) == 0) {                 // XCD swizzle (384 % 8 == 0)
    int cpx = nwg >> 3;
    bid = (bid & 7) * cpx + (bid >> 3);
  }
  const int bm = bid / nbn, bn = bid % nbn;

  const int tid = threadIdx.x;
  const int lane = tid & 63, wave = tid >> 6;
  const int g = lane >> 4, l15 = lane & 15;
  const int wm = wave >> 2, wn = wave & 3;   // wave tile: rows wm*128, cols wn*64

  const u16* Abase = A + (size_t)(bm << 8) * K;
  const u16* Bbase = Bt + (size_t)(bn << 8) * K;

  // staging: region = 256 rows x 32 k = 1024 chunks of 16B; thread does
  // chunks tid and 512+tid. chunk c: row=c>>2, kc=(c&3)^((row>>1)&3) pre-swz.
  const int cA = tid, rA = cA >> 2;
  const int cB = 512 + tid, rB = cB >> 2;
  const size_t soff0 = (size_t)rA * K + (((cA & 3) ^ ((rA >> 1) & 3)) * 8);
  const size_t soff1 = (size_t)rB * K + (((cB & 3) ^ ((rB >> 1) & 3)) * 8);
  const int doff0 = cA * 8, doff1 = cB * 8;

  auto stageS = [&](int buf, int s, int kt) {  // 4 gloads: A_khs + B_khs of tile kt
    const size_t kof = (size_t)kt * 64 + s * 32;
    gload_lds16(Abase + kof + soff0, &L[buf][s][0] + doff0);
    gload_lds16(Abase + kof + soff1, &L[buf][s][0] + doff1);
    gload_lds16(Bbase + kof + soff0, &L[buf][2 + s][0] + doff0);
    gload_lds16(Bbase + kof + soff1, &L[buf][2 + s][0] + doff1);
  };

  f32x4 zero = {0.f, 0.f, 0.f, 0.f};
  f32x4 acc[8][4];
#pragma unroll
  for (int i = 0; i < 8; ++i)
#pragma unroll
    for (int j = 0; j < 4; ++j) acc[i][j] = zero;

  const int NT = K >> 6;   // 16 K-tiles of 64

  // prologue: S(kh0,t0), S(kh1,t0); wait oldest group; publish.
  stageS(0, 0, 0);
  stageS(0, 1, 0);
  asm volatile("s_waitcnt vmcnt(4)" ::: "memory");
  __builtin_amdgcn_s_barrier();
  __builtin_amdgcn_sched_barrier(0);

#pragma unroll 1
  for (int kt = 0; kt < NT; ++kt) {
    const int cbuf = kt & 1, nbuf = cbuf ^ 1;
    const bool more = (kt + 1 < NT);
    const char* A0 = (const char*)&L[cbuf][0][0];
    const char* A1 = (const char*)&L[cbuf][1][0];
    const char* B0 = (const char*)&L[cbuf][2][0];
    const char* B1 = (const char*)&L[cbuf][3][0];

    bf16x8 af[4], bf[4];
    // ---- P1: ksub0, A rows-half 0 + all B(kh0) ----
#pragma unroll
    for (int i = 0; i < 4; ++i) {
      int ra = wm * 128 + i * 16 + l15;
      af[i] = *(const bf16x8*)(A0 + ra * 64 + ((g ^ ((ra >> 1) & 3)) << 4));
    }
#pragma unroll
    for (int j = 0; j < 4; ++j) {
      int rb = wn * 64 + j * 16 + l15;
      bf[j] = *(const bf16x8*)(B0 + rb * 64 + ((g ^ ((rb >> 1) & 3)) << 4));
    }
    if (more) stageS(nbuf, 0, kt + 1);
    asm volatile("s_waitcnt lgkmcnt(0)" ::: "memory");
    __builtin_amdgcn_sched_barrier(0);
    __builtin_amdgcn_s_setprio(1);
#pragma unroll
    for (int i = 0; i < 4; ++i)
#pragma unroll
      for (int j = 0; j < 4; ++j)
        acc[i][j] = __builtin_amdgcn_mfma_f32_16x16x32_bf16(af[i], bf[j], acc[i][j], 0, 0, 0);
    __builtin_amdgcn_s_setprio(0);
    __builtin_amdgcn_s_barrier();
    __builtin_amdgcn_sched_barrier(0);

    // ---- P2: ksub0, A rows-half 1 (B held in regs) ----
#pragma unroll
    for (int i = 0; i < 4; ++i) {
      int ra = wm * 128 + (i + 4) * 16 + l15;
      af[i] = *(const bf16x8*)(A0 + ra * 64 + ((g ^ ((ra >> 1) & 3)) << 4));
    }
    asm volatile("s_waitcnt lgkmcnt(0)" ::: "memory");
    __builtin_amdgcn_sched_barrier(0);
    __builtin_amdgcn_s_setprio(1);
#pragma unroll
    for (int i = 0; i < 4; ++i)
#pragma unroll
      for (int j = 0; j < 4; ++j)
        acc[i + 4][j] = __builtin_amdgcn_mfma_f32_16x16x32_bf16(af[i], bf[j], acc[i + 4][j], 0, 0, 0);
    __builtin_amdgcn_s_setprio(0);
    // publish S(kh1, kt): newest group (S kh0,kt+1) may stay in flight
    if (more) asm volatile("s_waitcnt vmcnt(4)" ::: "memory");
    else      asm volatile("s_waitcnt vmcnt(0)" ::: "memory");
    __builtin_amdgcn_s_barrier();
    __builtin_amdgcn_sched_barrier(0);

    // ---- P3: ksub1, A rows-half 0 + all B(kh1) ----
#pragma unroll
    for (int i = 0; i < 4; ++i) {
      int ra = wm * 128 + i * 16 + l15;
      af[i] = *(const bf16x8*)(A1 + ra * 64 + ((g ^ ((ra >> 1) & 3)) << 4));
    }
#pragma unroll
    for (int j = 0; j < 4; ++j) {
      int rb = wn * 64 + j * 16 + l15;
      bf[j] = *(const bf16x8*)(B1 + rb * 64 + ((g ^ ((rb >> 1) & 3)) << 4));
    }
    if (more) stageS(nbuf, 1, kt + 1);
    asm volatile("s_waitcnt lgkmcnt(0)" ::: "memory");
    __builtin_amdgcn_sched_barrier(0);
    __builtin_amdgcn_s_setprio(1);
#pragma unroll
    for (int i = 0; i < 4; ++i)
#pragma unroll
      for (int j = 0; j < 4; ++j)
        acc[i][j] = __builtin_amdgcn_mfma_f32_16x16x32_bf16(af[i], bf[j], acc[i][j], 0, 0, 0);
    __builtin_amdgcn_s_setprio(0);
    __builtin_amdgcn_s_barrier();
    __builtin_amdgcn_sched_barrier(0);

    // ---- P4: ksub1, A rows-half 1 ----
#pragma unroll
    for (int i = 0; i < 4; ++i) {
      int ra = wm * 128 + (i + 4) * 16 + l15;
      af[i] = *(const bf16x8*)(A1 + ra * 64 + ((g ^ ((ra >> 1) & 3)) << 4));
    }
    asm volatile("s_waitcnt lgkmcnt(0)" ::: "memory");
    __builtin_amdgcn_sched_barrier(0);
    __builtin_amdgcn_s_setprio(1);
#pragma unroll
    for (int i = 0; i < 4; ++i)
#pragma unroll
      for (int j = 0; j < 4; ++j)
        acc[i + 4][j] = __builtin_amdgcn_mfma_f32_16x16x32_bf16(af[i], bf[j], acc[i + 4][j], 0, 0, 0);
    __builtin_amdgcn_s_setprio(0);
    // publish S(kh0, kt+1): newest group (S kh1,kt+1) may stay in flight
    if (more) asm volatile("s_waitcnt vmcnt(4)" ::: "memory");
    else      asm volatile("s_waitcnt vmcnt(0)" ::: "memory");
    __builtin_amdgcn_s_barrier();
    __builtin_amdgcn_sched_barrier(0);
  }

#pragma unroll
  for (int i = 0; i < 8; ++i) {
    int row0 = (bm << 8) + wm * 128 + i * 16 + g * 4;
#pragma unroll
    for (int j = 0; j < 4; ++j) {
      int col = (bn << 8) + wn * 64 + j * 16 + l15;
      float bv = bias[col];
      const bool qc = col < qcols;
#pragma unroll
      for (int r = 0; r < 4; ++r) {
        float v = acc[i][j][r] + bv;
        if (qc) v *= QSCALE_CONST;
        Cmat[(size_t)(row0 + r) * N + col] = f2bf(v);
      }
    }
  }
}

// ---------------- 128x128 bf16 GEMM (ring), used for the small GEMM2 ----------------
template <typename OutT>
__global__ __launch_bounds__(256, 3) void gemm_bf16_kernel(
    const u16* __restrict__ A, const u16* __restrict__ Bt,
    const float* __restrict__ bias, OutT* __restrict__ Cmat,
    int M, int N, int K, int qcols) {
  __shared__ __attribute__((aligned(16))) u16 As[3][128 * 32];
  __shared__ __attribute__((aligned(16))) u16 Bs[3][128 * 32];

  const int nbn = N >> 7;
  const int nwg = (M >> 7) * nbn;
  int bid = blockIdx.x;
  if ((nwg & 7) == 0) {
    int cpx = nwg >> 3;
    bid = (bid & 7) * cpx + (bid >> 3);
  }
  const int bm = bid / nbn, bn = bid % nbn;

  const int tid = threadIdx.x;
  const int lane = tid & 63, wave = tid >> 6;
  const int g = lane >> 4, l15 = lane & 15;
  const int wrow = (wave >> 1) << 6, wcol = (wave & 1) << 6;

  const u16* Abase = A + (size_t)(bm << 7) * K;
  const u16* Bbase = Bt + (size_t)(bn << 7) * K;

  const int c0_ = wave * 64 + lane, c1_ = 256 + c0_;
  const int row0_ = c0_ >> 2, row1_ = c1_ >> 2;
  const size_t soff0 = (size_t)row0_ * K + ((c0_ & 3) ^ (row0_ & 3)) * 8;
  const size_t soff1 = (size_t)row1_ * K + ((c1_ & 3) ^ (row1_ & 3)) * 8;
  const int doff0 = c0_ * 8, doff1 = c1_ * 8;

  auto stage = [&](int buf, int k0) {
    gload_lds16(Abase + k0 + soff0, As[buf] + doff0);
    gload_lds16(Bbase + k0 + soff0, Bs[buf] + doff0);
    gload_lds16(Abase + k0 + soff1, As[buf] + doff1);
    gload_lds16(Bbase + k0 + soff1, Bs[buf] + doff1);
  };

  f32x4 zero = {0.f, 0.f, 0.f, 0.f};
  f32x4 acc[4][4];
#pragma unroll
  for (int i = 0; i < 4; ++i)
#pragma unroll
    for (int j = 0; j < 4; ++j) acc[i][j] = zero;

  const int NT = K >> 5;
  stage(0, 0);
  stage(1, 32);
#pragma unroll 1
  for (int kt = 0; kt < NT; ++kt) {
    const int cur = kt % 3;
    asm volatile("s_waitcnt lgkmcnt(0)" ::: "memory");
    __builtin_amdgcn_sched_barrier(0);
    if (kt < NT - 1) asm volatile("s_waitcnt vmcnt(4)" ::: "memory");
    else             asm volatile("s_waitcnt vmcnt(0)" ::: "memory");
    __builtin_amdgcn_s_barrier();
    if (kt + 2 < NT) stage((kt + 2) % 3, (kt + 2) << 5);

    const char* Ab = (const char*)As[cur];
    const char* Bb = (const char*)Bs[cur];
    bf16x8 af[4], bfr[4];
#pragma unroll
    for (int i = 0; i < 4; ++i) {
      int ra = wrow + i * 16 + l15;
      af[i] = *(const bf16x8*)(Ab + ra * 64 + ((g * 16) ^ ((ra & 3) << 4)));
      int rb = wcol + i * 16 + l15;
      bfr[i] = *(const bf16x8*)(Bb + rb * 64 + ((g * 16) ^ ((rb & 3) << 4)));
    }
#pragma unroll
    for (int i = 0; i < 4; ++i)
#pragma unroll
      for (int j = 0; j < 4; ++j)
        acc[i][j] = __builtin_amdgcn_mfma_f32_16x16x32_bf16(af[i], bfr[j], acc[i][j], 0, 0, 0);
  }

#pragma unroll
  for (int i = 0; i < 4; ++i) {
    int row0 = (bm << 7) + wrow + i * 16 + g * 4;
#pragma unroll
    for (int j = 0; j < 4; ++j) {
      int col = (bn << 7) + wcol + j * 16 + l15;
      float bv = bias[col];
      const bool qc = col < qcols;
#pragma unroll
      for (int r = 0; r < 4; ++r) {
        float v = acc[i][j][r] + bv;
        if (qc) v *= QSCALE_CONST;
        size_t idx = (size_t)(row0 + r) * N + col;
        if constexpr (sizeof(OutT) == 2)
          ((u16*)Cmat)[idx] = f2bf(v);
        else
          ((float*)Cmat)[idx] = v;
      }
    }
  }
}

// ---------------- flash attention v6 (causal), B=4 H=16 T=2048 Dh=64 ----------------
// grid (B*H=64, 8), 256 threads (4 waves). Wave owns 32 q-rows (two 16-row
// groups A/B) -> each K/V LDS fragment read feeds TWO MFMAs. blockIdx.x = bh
// -> same-head blocks on same XCD. Supertile pair {j, 15-j}: uniform 36 steps.
// Swapped QK^T, fixed-max softmax folded into acc init, cvt_pk P pack.
__global__ __launch_bounds__(256, 2) void attn_kernel(
    const u16* __restrict__ qkv, u16* __restrict__ aout) {
  __shared__ __attribute__((aligned(16))) char KsB[2][8192];  // K tile [64kv][64d]
  __shared__ __attribute__((aligned(16))) char VtB[2][8192];  // V^T [64d][64kv]
  __shared__ __attribute__((aligned(16))) char PbB[4][4096];  // per-wave P [32q][64kv]

  const int bh = blockIdx.x;
  const int b = bh >> 4, h = bh & 15;
  const int tid = threadIdx.x, lane = tid & 63, wave = tid >> 6;
  const int g = lane >> 4, l15 = lane & 15;

  const u16* qbase = qkv + (size_t)b * 2048 * 3072 + h * 64;
  const u16* kbase = qbase + 1024;
  const u16* vbase = qbase + 2048;

  const int krow0 = tid >> 3;
  const int ksc = (tid & 7) ^ (krow0 & 7);
  const size_t ksrc0 = (size_t)krow0 * 3072 + ksc * 8;
  const size_t ksrc1 = ksrc0 + (size_t)32 * 3072;
  const int vp_ = tid >> 3, vdh = tid & 7;
  const size_t vsrc = (size_t)(2 * vp_) * 3072 + vdh * 8;
  const int vkc = vp_ >> 2, vofs = (vp_ & 3) << 2;

  char* pb = PbB[wave];
  const f32x4 sinit = {-SMAX_CONST, -SMAX_CONST, -SMAX_CONST, -SMAX_CONST};
  f32x4 zero = {0.f, 0.f, 0.f, 0.f};

#pragma unroll 1
  for (int jj = 0; jj < 2; ++jj) {
    const int j = jj ? (15 - blockIdx.y) : blockIdx.y;
    const int q0 = j << 7;
    const int qrow = q0 + wave * 32;
    const int nt = 2 * j + 2;

    bf16x8 qfA[2], qfB[2];
#pragma unroll
    for (int kf = 0; kf < 2; ++kf) {
      qfA[kf] = *(const bf16x8*)(qbase + (size_t)(qrow + l15) * 3072 + kf * 32 + g * 8);
      qfB[kf] = *(const bf16x8*)(qbase + (size_t)(qrow + 16 + l15) * 3072 + kf * 32 + g * 8);
    }

    float lsumA = 0.f, lsumB = 0.f;
    f32x4 oA[4], oB[4];
#pragma unroll
    for (int d = 0; d < 4; ++d) { oA[d] = zero; oB[d] = zero; }

    gload_lds16(kbase + ksrc0, KsB[0] + wave * 1024);
    gload_lds16(kbase + ksrc1, KsB[0] + 4096 + wave * 1024);
    {
      bf16x8 v0 = *(const bf16x8*)(vbase + vsrc);
      bf16x8 v1 = *(const bf16x8*)(vbase + vsrc + 3072);
      char* vb = VtB[0];
#pragma unroll
      for (int q = 0; q < 8; ++q) {
        int d = vdh * 8 + q;
        int sig = q ^ vdh;
        unsigned pack = (unsigned)(u16)v0[q] | ((unsigned)(u16)v1[q] << 16);
        *(unsigned*)(vb + d * 128 + ((vkc ^ sig) << 4) + vofs) = pack;
      }
    }

    bf16x8 nv0, nv1;
#pragma unroll 1
    for (int t = 0; t < nt; ++t) {
      const int cur = t & 1;
      const int kv0 = t << 6;
      const bool pre = (t + 1 < nt);
      __syncthreads();

      if (pre) {
        const size_t nxt = (size_t)(t + 1) * 196608;
        gload_lds16(kbase + nxt + ksrc0, KsB[cur ^ 1] + wave * 1024);
        gload_lds16(kbase + nxt + ksrc1, KsB[cur ^ 1] + 4096 + wave * 1024);
        nv0 = *(const bf16x8*)(vbase + nxt + vsrc);
        nv1 = *(const bf16x8*)(vbase + nxt + vsrc + 3072);
      }

      if (qrow + 31 >= kv0) {
        const char* ks = KsB[cur];
        f32x4 sA[4], sB[4];
#pragma unroll
        for (int n = 0; n < 4; ++n) { sA[n] = sinit; sB[n] = sinit; }
#pragma unroll
        for (int kf = 0; kf < 2; ++kf)
#pragma unroll
          for (int n = 0; n < 4; ++n) {
            int row = n * 16 + l15;
            bf16x8 kfr = *(const bf16x8*)(ks + row * 128 + (((kf * 4 + g) ^ (row & 7)) << 4));
            sA[n] = __builtin_amdgcn_mfma_f32_16x16x32_bf16(kfr, qfA[kf], sA[n], 0, 0, 0);
            sB[n] = __builtin_amdgcn_mfma_f32_16x16x32_bf16(kfr, qfB[kf], sB[n], 0, 0, 0);
          }

        const int kvb = kv0 + g * 4;
        if (kv0 + 63 > qrow) {
          const int qgA = qrow + l15;
#pragma unroll
          for (int n = 0; n < 4; ++n)
#pragma unroll
            for (int r = 0; r < 4; ++r)
              if (kvb + n * 16 + r > qgA) sA[n][r] = -1e30f;
        }
        if (kv0 + 63 > qrow + 16) {
          const int qgB = qrow + 16 + l15;
#pragma unroll
          for (int n = 0; n < 4; ++n)
#pragma unroll
            for (int r = 0; r < 4; ++r)
              if (kvb + n * 16 + r > qgB) sB[n][r] = -1e30f;
        }

        float rsA = 0.f, rsB = 0.f;
#pragma unroll
        for (int n = 0; n < 4; ++n)
#pragma unroll
          for (int r = 0; r < 4; ++r) {
            float pA = __builtin_amdgcn_exp2f(sA[n][r]);
            float pB = __builtin_amdgcn_exp2f(sB[n][r]);
            sA[n][r] = pA; rsA += pA;
            sB[n][r] = pB; rsB += pB;
          }
        lsumA += rsA; lsumB += rsB;

#pragma unroll
        for (int n = 0; n < 4; ++n) {
          uint2 wA, wB;
          asm("v_cvt_pk_bf16_f32 %0, %1, %2" : "=v"(wA.x) : "v"(sA[n][0]), "v"(sA[n][1]));
          asm("v_cvt_pk_bf16_f32 %0, %1, %2" : "=v"(wA.y) : "v"(sA[n][2]), "v"(sA[n][3]));
          asm("v_cvt_pk_bf16_f32 %0, %1, %2" : "=v"(wB.x) : "v"(sB[n][0]), "v"(sB[n][1]));
          asm("v_cvt_pk_bf16_f32 %0, %1, %2" : "=v"(wB.y) : "v"(sB[n][2]), "v"(sB[n][3]));
          int c = n * 2 + (g >> 1);
          int boff = (((c ^ (l15 & 7)) << 4) | ((g & 1) << 3)) + l15 * 128;
          *(uint2*)(pb + boff) = wA;
          *(uint2*)(pb + 2048 + boff) = wB;
        }

        const char* vt = VtB[cur];
        bf16x8 pfA[2], pfB[2];
#pragma unroll
        for (int kf = 0; kf < 2; ++kf) {
          int poff = l15 * 128 + (((kf * 4 + g) ^ (l15 & 7)) << 4);
          pfA[kf] = *(const bf16x8*)(pb + poff);
          pfB[kf] = *(const bf16x8*)(pb + 2048 + poff);
        }
#pragma unroll
        for (int kf = 0; kf < 2; ++kf)
#pragma unroll
          for (int d = 0; d < 4; ++d) {
            int dr = d * 16 + l15;
            int sig = (dr & 7) ^ ((dr >> 3) & 7);
            bf16x8 vf = *(const bf16x8*)(vt + dr * 128 + (((kf * 4 + g) ^ sig) << 4));
            oA[d] = __builtin_amdgcn_mfma_f32_16x16x32_bf16(pfA[kf], vf, oA[d], 0, 0, 0);
            oB[d] = __builtin_amdgcn_mfma_f32_16x16x32_bf16(pfB[kf], vf, oB[d], 0, 0, 0);
          }
      }

      if (pre) {
        char* vb = VtB[cur ^ 1];
#pragma unroll
        for (int q = 0; q < 8; ++q) {
          int d = vdh * 8 + q;
          int sig = q ^ vdh;
          unsigned pack = (unsigned)(u16)nv0[q] | ((unsigned)(u16)nv1[q] << 16);
          *(unsigned*)(vb + d * 128 + ((vkc ^ sig) << 4) + vofs) = pack;
        }
      }
    }

    lsumA += __shfl_xor(lsumA, 16); lsumA += __shfl_xor(lsumA, 32);
    lsumB += __shfl_xor(lsumB, 16); lsumB += __shfl_xor(lsumB, 32);
    float invA[4], invB[4];
#pragma unroll
    for (int r = 0; r < 4; ++r) {
      invA[r] = __builtin_amdgcn_rcpf(__shfl(lsumA, g * 4 + r));
      invB[r] = __builtin_amdgcn_rcpf(__shfl(lsumB, g * 4 + r));
    }
    const size_t obase = (size_t)(b * 2048 + qrow) * 1024 + h * 64;
#pragma unroll
    for (int d = 0; d < 4; ++d)
#pragma unroll
      for (int r = 0; r < 4; ++r) {
        aout[obase + (size_t)(g * 4 + r) * 1024 + d * 16 + l15] = f2bf(oA[d][r] * invA[r]);
        aout[obase + (size_t)(16 + g * 4 + r) * 1024 + d * 16 + l15] = f2bf(oB[d][r] * invB[r]);
      }
  }
}

// ---------------- host launch ----------------
extern "C" void kernel_launch(void* const* d_in, const int* in_sizes, int n_in,
                              void* d_out, int out_size, void* d_ws, size_t ws_size,
                              hipStream_t stream) {
  const float* x      = (const float*)d_in[0];
  const float* W_attn = (const float*)d_in[1];
  const float* b_attn = (const float*)d_in[2];
  const float* W_proj = (const float*)d_in[3];
  const float* b_proj = (const float*)d_in[4];
  float* out = (float*)d_out;

  char* ws = (char*)d_ws;
  u16* xb   = (u16*)(ws);                                // 16 MB: x bf16 [8192,1024]
  u16* Wat  = (u16*)(ws + (size_t)16 * 1024 * 1024);     //  6 MB: W_attn^T bf16 [3072,1024]
  u16* Wpt  = (u16*)(ws + (size_t)22 * 1024 * 1024);     //  2 MB: W_proj^T bf16 [1024,1024]
  u16* qkv  = (u16*)(ws + (size_t)24 * 1024 * 1024);     // 48 MB: qkv bf16 [8192,3072] (q pre-scaled)
  u16* aout = (u16*)(ws + (size_t)72 * 1024 * 1024);     // 16 MB: attn out bf16 [8192,1024]

  cast_bf16_kernel<<<8192, 256, 0, stream>>>(x, xb, 8388608);
  transpose_cast_kernel<<<dim3(96, 32), 256, 0, stream>>>(W_attn, Wat, 1024, 3072);
  transpose_cast_kernel<<<dim3(32, 32), 256, 0, stream>>>(W_proj, Wpt, 1024, 1024);
  gemm256_kernel<<<384, 512, 0, stream>>>(xb, Wat, b_attn, qkv, 8192, 3072, 1024, 1024);
  attn_kernel<<<dim3(64, 8), 256, 0, stream>>>(qkv, aout);
  gemm_bf16_kernel<float><<<512, 256, 0, stream>>>(aout, Wpt, b_proj, out, 8192, 1024, 1024, 0);
}